// Round 1
// baseline (112.709 us; speedup 1.0000x reference)
//
#include <hip/hip_runtime.h>

// out[b,h,i,j] = x[b,h,i,j] * clamp(((ring(i,j)-127) + cv*256)/32 + 1, 0, 1)
// ring(i,j) = min(i, j, 255-i, 255-j), plane is 256x256, fp32, memory-bound.

__global__ __launch_bounds__(256) void AdaptiveMask_kernel(
    const float4* __restrict__ x,
    const float* __restrict__ cvp,
    float4* __restrict__ out,
    int total4)
{
    // cv*256: single read, L2-broadcast. Rounding order matches reference:
    // t = (ring-127) + cv256  (1 round); t * (1/32) exact; +1 (1 round); clamp.
    const float cv256 = cvp[0] * 256.0f;

    int idx = blockIdx.x * blockDim.x + threadIdx.x;
    const int stride = gridDim.x * blockDim.x;

    for (int i = idx; i < total4; i += stride) {
        const int e = i << 2;            // element index
        const int r = (e >> 8) & 255;    // row within 256x256 plane
        const int c = e & 255;           // col of first of 4 consecutive elems
        const int rr = min(r, 255 - r);  // row contribution to ring

        float4 v = x[i];
        float4 o;

        {
            const int col = c + 0;
            const int ring = min(rr, min(col, 255 - col));
            const float t = (float)(ring - 127) + cv256;
            const float m = fminf(fmaxf(t * 0.03125f + 1.0f, 0.0f), 1.0f);
            o.x = v.x * m;
        }
        {
            const int col = c + 1;
            const int ring = min(rr, min(col, 255 - col));
            const float t = (float)(ring - 127) + cv256;
            const float m = fminf(fmaxf(t * 0.03125f + 1.0f, 0.0f), 1.0f);
            o.y = v.y * m;
        }
        {
            const int col = c + 2;
            const int ring = min(rr, min(col, 255 - col));
            const float t = (float)(ring - 127) + cv256;
            const float m = fminf(fmaxf(t * 0.03125f + 1.0f, 0.0f), 1.0f);
            o.z = v.z * m;
        }
        {
            const int col = c + 3;
            const int ring = min(rr, min(col, 255 - col));
            const float t = (float)(ring - 127) + cv256;
            const float m = fminf(fmaxf(t * 0.03125f + 1.0f, 0.0f), 1.0f);
            o.w = v.w * m;
        }

        out[i] = o;
    }
}

extern "C" void kernel_launch(void* const* d_in, const int* in_sizes, int n_in,
                              void* d_out, int out_size, void* d_ws, size_t ws_size,
                              hipStream_t stream) {
    const float4* x  = (const float4*)d_in[0];
    const float*  cv = (const float*)d_in[1];
    float4* out = (float4*)d_out;

    const int total4 = out_size / 4;   // 32*8*256*256 / 4 = 4,194,304

    const int block = 256;
    const int grid  = 2048;            // 256 CUs * 8 blocks/CU; grid-stride x8

    AdaptiveMask_kernel<<<grid, block, 0, stream>>>(x, cv, out, total4);
}